// Round 4
// baseline (187.060 us; speedup 1.0000x reference)
//
#include <hip/hip_runtime.h>
#include <math.h>

// Problem constants (from reference)
#define GRID_HW   13
#define NBOX      5
#define NCLASS    80
#define REC       85                       // 5 + NCLASS floats per cell
#define CPB_CELLS (GRID_HW*GRID_HW*NBOX)   // 845 cells per batch element
#define T_BOXES   50
#define THREADS   256
#define QPB       (THREADS/4)              // 64 cells per block

__device__ __constant__ float c_anchors[10] = {
    0.57273f, 0.677385f, 1.87446f, 2.06253f, 3.33843f,
    5.47434f, 7.88282f, 3.52778f, 9.77052f, 9.16828f};

// partial layout per block row (64 B): [0]=sum_xy [1]=sum_wh [2]=sum_conf
// [3]=sum_ce [4]=nb_coord [5]=nb_conf [6]=nb_class [7]=0 (pad for double4)
template <int USE_ATOMIC>
__global__ __launch_bounds__(THREADS, 6)
void yolo_loss_main(const float* __restrict__ y_true,
                    const float* __restrict__ y_pred,
                    const float* __restrict__ tboxes,
                    double* __restrict__ partials,
                    int n_cells)
{
    __shared__ double red[4][8];

    const int tid  = threadIdx.x;
    const int lane = tid & 63;
    const int q    = tid & 3;     // lane within quad
    const int quad = tid >> 2;    // cell within block
    const int cell = blockIdx.x * QPB + quad;

    double p_xy = 0.0, p_wh = 0.0, p_conf = 0.0, p_ce = 0.0;
    double p_nc = 0.0, p_nf = 0.0, p_ncl = 0.0;

    if (cell < n_cells) {
        // decode (b, h, w, box)
        int b    = cell / CPB_CELLS;
        int rem  = cell - b * CPB_CELLS;
        int h    = rem / (GRID_HW * NBOX);
        int rem2 = rem - h * (GRID_HW * NBOX);
        int w    = rem2 / NBOX;
        int box  = rem2 - w * NBOX;

        const float* __restrict__ yt = y_true + (size_t)cell * REC;
        const float* __restrict__ yp = y_pred + (size_t)cell * REC;

        // ---- cooperative head load (2 instrs) + quad shuffle broadcast ----
        const float A  = yt[q];
        const float Bv = yp[q];
        const float yt4 = yt[4];
        const float r4  = yp[4];
        const int qb = lane & ~3;
        const float tx = __shfl(A, qb),     ty = __shfl(A, qb | 1);
        const float tw = __shfl(A, qb | 2), th = __shfl(A, qb | 3);
        const float r0 = __shfl(Bv, qb),     r1 = __shfl(Bv, qb | 1);
        const float r2 = __shfl(Bv, qb | 2), r3 = __shfl(Bv, qb | 3);

        // predicted box (redundant across the 4 quad lanes; cheap)
        const float px = 1.f / (1.f + expf(-r0)) + (float)w;
        const float py = 1.f / (1.f + expf(-r1)) + (float)h;
        const float pw = expf(r2) * c_anchors[2 * box];
        const float ph = expf(r3) * c_anchors[2 * box + 1];
        const float pconf = 1.f / (1.f + expf(-r4));

        const float pw2 = pw * 0.5f, ph2 = ph * 0.5f;
        const float p_minx = px - pw2, p_maxx = px + pw2;
        const float p_miny = py - ph2, p_maxy = py + ph2;

        // IoU vs y_true box -> true_box_conf
        float tw2 = tw * 0.5f, th2 = th * 0.5f;
        float iw = fmaxf(fminf(p_maxx, tx + tw2) - fmaxf(p_minx, tx - tw2), 0.f);
        float ih = fmaxf(fminf(p_maxy, ty + th2) - fmaxf(p_miny, ty - th2), 0.f);
        float inter = iw * ih;
        float iou = inter / (pw * ph + tw * th - inter);
        const float true_conf = iou * yt4;

        // ---- alignment-aware float4 class loads ----
        // class array starts at dword 85*cell + 5; (85c+5) mod 4 == (c+1) mod 4
        const int pD = 3 - (cell & 3);           // leading scalars (0..3)
        const int n4 = (NCLASS - pD) >> 2;       // 19 or 20 aligned float4 chunks
        const int tr = NCLASS - pD - (n4 << 2);  // trailing scalars (0..3)
        const float* __restrict__ ct = yt + 5;
        const float* __restrict__ cp = yp + 5;
        const float4* __restrict__ v4t = (const float4*)(ct + pD);
        const float4* __restrict__ v4p = (const float4*)(cp + pD);

        const float NEG = -INFINITY;
        float amax = NEG; int aidx = 0x7fffffff;
        float lmax = NEG;
        float pvv[20];

        #pragma unroll
        for (int j = 0; j < 5; ++j) {
            const int g = q + 4 * j;             // chunk index for this lane
            float4 ft = make_float4(NEG, NEG, NEG, NEG);
            float4 fp = make_float4(NEG, NEG, NEG, NEG);
            if (g < n4) { ft = v4t[g]; fp = v4p[g]; }
            const int i0 = pD + 4 * g;
            if (ft.x > amax || (ft.x == amax && i0     < aidx)) { amax = ft.x; aidx = i0;     }
            if (ft.y > amax || (ft.y == amax && i0 + 1 < aidx)) { amax = ft.y; aidx = i0 + 1; }
            if (ft.z > amax || (ft.z == amax && i0 + 2 < aidx)) { amax = ft.z; aidx = i0 + 2; }
            if (ft.w > amax || (ft.w == amax && i0 + 3 < aidx)) { amax = ft.w; aidx = i0 + 3; }
            lmax = fmaxf(lmax, fmaxf(fmaxf(fp.x, fp.y), fmaxf(fp.z, fp.w)));
            pvv[4 * j]     = fp.x;
            pvv[4 * j + 1] = fp.y;
            pvv[4 * j + 2] = fp.z;
            pvv[4 * j + 3] = fp.w;
        }
        // leading + trailing scalars (<=1 each per lane)
        float lead_t = NEG, lead_p = NEG, trail_t = NEG, trail_p = NEG;
        const int tb0 = pD + (n4 << 2);
        if (q < pD) { lead_t  = ct[q];      lead_p  = cp[q];      }
        if (q < tr) { trail_t = ct[tb0 + q]; trail_p = cp[tb0 + q]; }
        if (lead_t  > amax || (lead_t  == amax && q       < aidx)) { amax = lead_t;  aidx = q;       }
        if (trail_t > amax || (trail_t == amax && tb0 + q < aidx)) { amax = trail_t; aidx = tb0 + q; }
        lmax = fmaxf(lmax, fmaxf(lead_p, trail_p));

        // cross-lane (quad) reduce: argmax w/ min-idx tiebreak, max
        #pragma unroll
        for (int m = 1; m <= 2; m <<= 1) {
            float ov = __shfl_xor(amax, m);
            int   oi = __shfl_xor(aidx, m);
            if (ov > amax || (ov == amax && oi < aidx)) { amax = ov; aidx = oi; }
            lmax = fmaxf(lmax, __shfl_xor(lmax, m));
        }

        // ---- pass 2: sum exp from registers (expf(-INF)=0 handles padding) ----
        float lsum = 0.f;
        #pragma unroll
        for (int j = 0; j < 20; ++j) lsum += expf(pvv[j] - lmax);
        lsum += expf(lead_p - lmax) + expf(trail_p - lmax);
        #pragma unroll
        for (int m = 1; m <= 2; m <<= 1)
            lsum += __shfl_xor(lsum, m);

        // selected logit: one scalar load (quad-broadcast, L1-hot)
        const float sel = cp[aidx];
        const float ce = -(sel - lmax - logf(lsum));

        // ---- best IoU over 50 true boxes (4-way split; broadcast across quads) ----
        const float4* tb = (const float4*)(tboxes + (size_t)b * T_BOXES * 4);
        float best = NEG;
        #pragma unroll 2
        for (int t = q; t < T_BOXES; t += 4) {
            float4 bx = tb[t];
            float bw2 = bx.z * 0.5f, bh2 = bx.w * 0.5f;
            float iw2 = fmaxf(fminf(p_maxx, bx.x + bw2) - fmaxf(p_minx, bx.x - bw2), 0.f);
            float ih2 = fmaxf(fminf(p_maxy, bx.y + bh2) - fmaxf(p_miny, bx.y - bh2), 0.f);
            float ia = iw2 * ih2;
            float r  = ia / (pw * ph + bx.z * bx.w - ia);
            best = fmaxf(best, r);
        }
        #pragma unroll
        for (int m = 1; m <= 2; m <<= 1)
            best = fmaxf(best, __shfl_xor(best, m));

        // ---- per-cell contributions (lane q==0 only) ----
        if (q == 0) {
            const float cm = yt4;  // coord_mask (COORD_FACTOR=1)
            p_xy = (double)(((tx - px) * (tx - px) + (ty - py) * (ty - py)) * cm);
            p_wh = (double)(((tw - pw) * (tw - pw) + (th - ph) * (th - ph)) * cm);
            float conf_mask = ((best < 0.6f) ? 1.f : 0.f) * (1.f - yt4)  // NO_OBJECT_FACTOR=1
                            + true_conf * 5.f;                            // OBJECT_FACTOR=5
            p_conf = (double)((true_conf - pconf) * (true_conf - pconf) * conf_mask);
            p_ce   = (double)(ce * yt4);                                  // CLASS_FACTOR=1
            p_nc   = (cm > 0.f)        ? 1.0 : 0.0;
            p_nf   = (conf_mask > 0.f) ? 1.0 : 0.0;
            p_ncl  = (yt4 > 0.f)       ? 1.0 : 0.0;
        }
    }

    // ---- block reduction (wave shfl -> LDS -> one 64B store per block) ----
    double v[7] = {p_xy, p_wh, p_conf, p_ce, p_nc, p_nf, p_ncl};
    #pragma unroll
    for (int k = 0; k < 7; ++k) {
        #pragma unroll
        for (int off = 32; off > 0; off >>= 1)
            v[k] += __shfl_down(v[k], off);
    }
    const int wave = tid >> 6, lane64 = tid & 63;
    if (lane64 == 0) {
        #pragma unroll
        for (int k = 0; k < 7; ++k) red[wave][k] = v[k];
    }
    __syncthreads();
    if (tid < 8) {
        double s = (tid < 7) ? (red[0][tid] + red[1][tid] + red[2][tid] + red[3][tid])
                             : 0.0;
        if (USE_ATOMIC) {
            if (tid < 7) unsafeAtomicAdd(&partials[tid], s);
        } else {
            partials[(size_t)blockIdx.x * 8 + tid] = s;   // contention-free store
        }
    }
}

// Reduce nblocks partial rows -> final scalar loss.
template <int USE_ATOMIC>
__global__ __launch_bounds__(1024)
void yolo_loss_final(const double* __restrict__ partials,
                     float* __restrict__ out, int nblocks)
{
    __shared__ double red[16][8];
    const int tid = threadIdx.x;

    if (USE_ATOMIC) {
        if (tid == 0) {
            double nbc  = partials[4] + 1e-6;
            double nbf  = partials[5] + 1e-6;
            double nbcl = partials[6] + 1e-6;
            out[0] = (float)(partials[0] / nbc * 0.5 + partials[1] / nbc * 0.5 +
                             partials[2] / nbf * 0.5 + partials[3] / nbcl);
        }
        return;
    }

    double v[7] = {0, 0, 0, 0, 0, 0, 0};
    for (int i = tid; i < nblocks; i += 1024) {
        const double4* p = (const double4*)(partials + (size_t)i * 8);  // 32B-aligned
        double4 a = p[0];
        double4 b = p[1];
        v[0] += a.x; v[1] += a.y; v[2] += a.z; v[3] += a.w;
        v[4] += b.x; v[5] += b.y; v[6] += b.z;   // b.w is the zero pad
    }
    #pragma unroll
    for (int k = 0; k < 7; ++k) {
        #pragma unroll
        for (int off = 32; off > 0; off >>= 1)
            v[k] += __shfl_down(v[k], off);
    }
    const int wave = tid >> 6, lane = tid & 63;
    if (lane == 0) {
        #pragma unroll
        for (int k = 0; k < 7; ++k) red[wave][k] = v[k];
    }
    __syncthreads();
    if (tid == 0) {
        double s[7];
        #pragma unroll
        for (int k = 0; k < 7; ++k) {
            double acc = 0.0;
            #pragma unroll
            for (int wv = 0; wv < 16; ++wv) acc += red[wv][k];
            s[k] = acc;
        }
        double nbc  = s[4] + 1e-6;
        double nbf  = s[5] + 1e-6;
        double nbcl = s[6] + 1e-6;
        out[0] = (float)(s[0] / nbc * 0.5 + s[1] / nbc * 0.5 +
                         s[2] / nbf * 0.5 + s[3] / nbcl);
    }
}

extern "C" void kernel_launch(void* const* d_in, const int* in_sizes, int n_in,
                              void* d_out, int out_size, void* d_ws, size_t ws_size,
                              hipStream_t stream)
{
    const float* y_true = (const float*)d_in[0];
    const float* y_pred = (const float*)d_in[1];
    const float* tboxes = (const float*)d_in[2];
    float* out  = (float*)d_out;
    double* ws  = (double*)d_ws;

    const int n_cells = in_sizes[0] / REC;                 // B*13*13*5 = 216320
    const int blocks  = (n_cells + QPB - 1) / QPB;         // 3380 for B=256
    const size_t need = (size_t)blocks * 8 * sizeof(double);

    if (ws_size >= need) {
        // contention-free path: per-block partial stores + tree reduce
        yolo_loss_main<0><<<blocks, THREADS, 0, stream>>>(y_true, y_pred, tboxes, ws, n_cells);
        yolo_loss_final<0><<<1, 1024, 0, stream>>>(ws, out, blocks);
    } else {
        // fallback: atomic accumulation into ws[0..6]
        hipMemsetAsync(d_ws, 0, 7 * sizeof(double), stream);
        yolo_loss_main<1><<<blocks, THREADS, 0, stream>>>(y_true, y_pred, tboxes, ws, n_cells);
        yolo_loss_final<1><<<1, 64, 0, stream>>>(ws, out, blocks);
    }
}